// Round 14
// baseline (351.866 us; speedup 1.0000x reference)
//
#include <hip/hip_runtime.h>
#include <hip/hip_bf16.h>
#include <stdint.h>

#define N_NODES 100000
#define N_EDGES 1600000
#define N_GRAPHS 64
#define HDIM 128

#define BUCKET_SHIFT 9
#define NBUCK ((N_NODES + 511) >> 9)                  // 196
#define CAP 9216                                      // per-bucket edge capacity (mean 8192 + 11 sigma)
#define SCAT_CHUNK 4096
#define SCAT_NBLK ((N_EDGES + SCAT_CHUNK - 1) / SCAT_CHUNK)  // 391
#define GB_NBLK ((N_NODES + 255) / 256)               // 391

typedef __bf16 bf16x8 __attribute__((ext_vector_type(8)));
typedef float f32x4 __attribute__((ext_vector_type(4)));
typedef float f32x2 __attribute__((ext_vector_type(2)));

// ---------------- fused setup: graph_bounds | transpose W1/W2 | init gcur/psum ----------------
__global__ __launch_bounds__(256) void setup_kernel(const int* __restrict__ batch,
                                                    int* __restrict__ gstart,
                                                    const float* __restrict__ W1,
                                                    const float* __restrict__ W2,
                                                    __hip_bfloat16* __restrict__ Wt1,
                                                    __hip_bfloat16* __restrict__ Wt2,
                                                    int* __restrict__ gcur,
                                                    float* __restrict__ psum) {
    int bid = blockIdx.x;
    if (bid < GB_NBLK) {
        // graph bounds (batch sorted)
        int i = bid * 256 + threadIdx.x;
        if (i >= N_NODES) return;
        int b = batch[i];
        int prev = (i == 0) ? -1 : batch[i - 1];
        for (int g = prev + 1; g <= b; ++g) gstart[g] = i;
        if (i == N_NODES - 1) {
            for (int g = b + 1; g <= N_GRAPHS; ++g) gstart[g] = N_NODES;
        }
    } else if (bid < GB_NBLK + 128) {
        // transpose W1/W2 -> bf16 Wt
        int t = bid - GB_NBLK;
        const float* W = (t < 64) ? W1 : W2;
        __hip_bfloat16* Wt = (t < 64) ? Wt1 : Wt2;
        int bb = t & 63;
        int n = bb * 2 + (threadIdx.x >> 7);
        int k = threadIdx.x & 127;
        Wt[n * 128 + k] = __float2bfloat16(W[k * 128 + n]);
    } else {
        // init gcur + psum
        int i = (bid - GB_NBLK - 128) * 256 + threadIdx.x;
        if (i < NBUCK) gcur[i] = i * CAP;
        int j = i - NBUCK;
        if (j >= 0 && j < N_GRAPHS * HDIM) psum[j] = 0.f;
    }
}
#define SETUP_NBLK (GB_NBLK + 128 + (NBUCK + N_GRAPHS * HDIM + 255) / 256)

// ---------------- scatter edges into capacity-strided buckets ----------------
// packed entry: (local_dst << 17) | src   (src < 2^17, local_dst < 512)
__global__ __launch_bounds__(256) void scatter_kernel(const int* __restrict__ src,
                                                      const int* __restrict__ dst,
                                                      int* __restrict__ gcur,
                                                      int* __restrict__ sorted, int E) {
    __shared__ int hist[NBUCK];
    __shared__ int base_s[NBUCK];
    int tid = threadIdx.x;
    int e0 = blockIdx.x * SCAT_CHUNK;
    int sv[SCAT_CHUNK / 256], dv[SCAT_CHUNK / 256];
#pragma unroll
    for (int j = 0; j < SCAT_CHUNK / 256; j++) {
        int e = e0 + (j << 8) + tid;
        if (e < E) { sv[j] = src[e]; dv[j] = dst[e]; } else { sv[j] = -1; dv[j] = -1; }
    }
    if (tid < NBUCK) hist[tid] = 0;
    __syncthreads();
#pragma unroll
    for (int j = 0; j < SCAT_CHUNK / 256; j++)
        if (dv[j] >= 0) atomicAdd(&hist[dv[j] >> BUCKET_SHIFT], 1);
    __syncthreads();
    if (tid < NBUCK) {
        int c = hist[tid];
        base_s[tid] = (c > 0) ? atomicAdd(&gcur[tid], c) : 0;
    }
    __syncthreads();
    if (tid < NBUCK) hist[tid] = 0;
    __syncthreads();
#pragma unroll
    for (int j = 0; j < SCAT_CHUNK / 256; j++) {
        if (dv[j] >= 0) {
            int b = dv[j] >> BUCKET_SHIFT;
            int idx = atomicAdd(&hist[b], 1);
            sorted[base_s[b] + idx] = ((dv[j] & 511) << 17) | sv[j];
        }
    }
}

// ---------------- per-bucket: degree, dis, row (start,end), CSR fill — one kernel ----------------
__global__ __launch_bounds__(256) void bucket_build_kernel(const int* __restrict__ sorted,
                                                           const int* __restrict__ gcur,
                                                           int2* __restrict__ rs2,
                                                           float* __restrict__ dis,
                                                           int* __restrict__ csr_src) {
    __shared__ int cnt[512];
    __shared__ int excl[512];
    __shared__ int ps[256];
    int b = blockIdx.x, tid = threadIdx.x;
    cnt[tid] = 0; cnt[tid + 256] = 0;
    __syncthreads();
    int node0 = b << BUCKET_SHIFT;
    int lo = b * CAP, hi = gcur[b];
    for (int i = lo + tid; i < hi; i += 256)
        atomicAdd(&cnt[((unsigned)sorted[i]) >> 17], 1);
    __syncthreads();
    // pair-scan of 512 counts with 256 threads
    int c0 = cnt[2 * tid], c1 = cnt[2 * tid + 1];
    ps[tid] = c0 + c1;
    __syncthreads();
#pragma unroll
    for (int off = 1; off < 256; off <<= 1) {
        int t = (tid >= off) ? ps[tid - off] : 0;
        __syncthreads();
        ps[tid] += t;
        __syncthreads();
    }
    int pex = ps[tid] - (c0 + c1);
    excl[2 * tid] = pex;
    excl[2 * tid + 1] = pex + c0;
    __syncthreads();
#pragma unroll
    for (int k = 0; k < 2; k++) {
        int li = tid + k * 256;
        int node = node0 + li;
        if (node < N_NODES) {
            int st = lo + excl[li];
            int c = cnt[li];
            rs2[node] = make_int2(st, st + c);
            dis[node] = rsqrtf((float)c + 1.0f);
        }
    }
    // reuse cnt as fill cursors
    cnt[tid] = 0; cnt[tid + 256] = 0;
    __syncthreads();
    for (int i = lo + tid; i < hi; i += 256) {
        int v = sorted[i];
        int li = ((unsigned)v) >> 17;
        int idx = atomicAdd(&cnt[li], 1);
        csr_src[lo + excl[li] + idx] = v & 0x1FFFF;
    }
}

// ---------------- MFMA GEMM: C_fp8[r][c] = e4m3( (sum_k A[r][k] W[k][c]) * scale[r] )
template<bool A_FP32>
__global__ __launch_bounds__(256) void gemm_mfma_kernel(const void* __restrict__ Av,
                                                        const __hip_bfloat16* __restrict__ Wt,
                                                        const float* __restrict__ scale,
                                                        unsigned char* __restrict__ C, int nrows) {
    __shared__ float Cs[64 * 132];
    int tid = threadIdx.x;
    int wave = tid >> 6, lane = tid & 63;
    int quad = lane >> 4, l16 = lane & 15;
    int row0 = blockIdx.x * 64;
    int arow = row0 + wave * 16 + l16;
    int arow_c = min(arow, nrows - 1);

    const __hip_bfloat16* A16 = (const __hip_bfloat16*)Av;
    const float* A32 = (const float*)Av;

    f32x4 acc[8];
#pragma unroll
    for (int t = 0; t < 8; t++) acc[t] = (f32x4){0.f, 0.f, 0.f, 0.f};

#pragma unroll
    for (int kt = 0; kt < 4; kt++) {
        int kbase = kt * 32 + quad * 8;
        union { bf16x8 v; __hip_bfloat16 h[8]; uint4 u; } au;
        if (A_FP32) {
            const float* ap = A32 + (size_t)arow_c * 128 + kbase;
            float4 u0 = *(const float4*)ap;
            float4 u1 = *(const float4*)(ap + 4);
            au.h[0] = __float2bfloat16(u0.x); au.h[1] = __float2bfloat16(u0.y);
            au.h[2] = __float2bfloat16(u0.z); au.h[3] = __float2bfloat16(u0.w);
            au.h[4] = __float2bfloat16(u1.x); au.h[5] = __float2bfloat16(u1.y);
            au.h[6] = __float2bfloat16(u1.z); au.h[7] = __float2bfloat16(u1.w);
        } else {
            au.u = *(const uint4*)(A16 + (size_t)arow_c * 128 + kbase);
        }
#pragma unroll
        for (int t = 0; t < 8; t++) {
            bf16x8 b = *(const bf16x8*)(Wt + (size_t)(t * 16 + l16) * 128 + kbase);
            acc[t] = __builtin_amdgcn_mfma_f32_16x16x32_bf16(au.v, b, acc[t], 0, 0, 0);
        }
    }

    int rbase = wave * 16 + quad * 4;
    float s[4];
#pragma unroll
    for (int r = 0; r < 4; r++) s[r] = scale[min(row0 + rbase + r, nrows - 1)];
#pragma unroll
    for (int t = 0; t < 8; t++) {
#pragma unroll
        for (int r = 0; r < 4; r++)
            Cs[(rbase + r) * 132 + t * 16 + l16] = acc[t][r] * s[r];
    }
    __syncthreads();

#pragma unroll
    for (int p = 0; p < 4; p++) {
        int g = p * 256 + tid;
        int row = g >> 4, c8 = (g & 15) * 8;
        int grow = row0 + row;
        if (grow < nrows) {
            const float* cp = &Cs[row * 132 + c8];
            float4 v0 = *(const float4*)cp;
            float4 v1 = *(const float4*)(cp + 4);
            int w0 = __builtin_amdgcn_cvt_pk_fp8_f32(v0.x, v0.y, 0, false);
            w0 = __builtin_amdgcn_cvt_pk_fp8_f32(v0.z, v0.w, w0, true);
            int w1 = __builtin_amdgcn_cvt_pk_fp8_f32(v1.x, v1.y, 0, false);
            w1 = __builtin_amdgcn_cvt_pk_fp8_f32(v1.z, v1.w, w1, true);
            *(uint2*)(C + (size_t)grow * 128 + c8) = make_uint2((unsigned)w0, (unsigned)w1);
        }
    }
}

// ---------------- GCN aggregation: 8 edges per gather instruction, 2-wide unroll ----------------
// lane = q*8 + f : slot q handles one edge, lane covers features f*16..f*16+15 (16 fp8 = 16 B)
__device__ __forceinline__ void accum16(float* acc, uint4 u) {
    f32x2 d0 = __builtin_amdgcn_cvt_pk_f32_fp8((int)u.x, false);
    f32x2 d1 = __builtin_amdgcn_cvt_pk_f32_fp8((int)u.x, true);
    f32x2 d2 = __builtin_amdgcn_cvt_pk_f32_fp8((int)u.y, false);
    f32x2 d3 = __builtin_amdgcn_cvt_pk_f32_fp8((int)u.y, true);
    f32x2 d4 = __builtin_amdgcn_cvt_pk_f32_fp8((int)u.z, false);
    f32x2 d5 = __builtin_amdgcn_cvt_pk_f32_fp8((int)u.z, true);
    f32x2 d6 = __builtin_amdgcn_cvt_pk_f32_fp8((int)u.w, false);
    f32x2 d7 = __builtin_amdgcn_cvt_pk_f32_fp8((int)u.w, true);
    acc[0] += d0[0];  acc[1] += d0[1];  acc[2] += d1[0];  acc[3] += d1[1];
    acc[4] += d2[0];  acc[5] += d2[1];  acc[6] += d3[0];  acc[7] += d3[1];
    acc[8] += d4[0];  acc[9] += d4[1];  acc[10] += d5[0]; acc[11] += d5[1];
    acc[12] += d6[0]; acc[13] += d6[1]; acc[14] += d7[0]; acc[15] += d7[1];
}

__global__ __launch_bounds__(256) void agg_kernel(const unsigned char* __restrict__ h8,
                                                  const float* __restrict__ dis,
                                                  const int2* __restrict__ rs2,
                                                  const int* __restrict__ csr_src,
                                                  const float* __restrict__ bias,
                                                  __hip_bfloat16* __restrict__ out, int n) {
    int node = blockIdx.x * 4 + (threadIdx.x >> 6);
    if (node >= n) return;
    int lane = threadIdx.x & 63;
    int q = lane >> 3, f = lane & 7;
    float acc[16];
#pragma unroll
    for (int j = 0; j < 16; j++) acc[j] = 0.f;
    int2 se = rs2[node];
    int i = se.x, i1 = se.y;
    // 2-wide unroll: 16 edges in flight from 2 gather instructions
    for (; i + 16 <= i1; i += 16) {
        int s0 = csr_src[i + q];
        int s1 = csr_src[i + 8 + q];
        uint4 u0 = *(const uint4*)(h8 + (size_t)s0 * 128 + f * 16);
        uint4 u1 = *(const uint4*)(h8 + (size_t)s1 * 128 + f * 16);
        accum16(acc, u0);
        accum16(acc, u1);
    }
    for (; i + 8 <= i1; i += 8) {
        int s = csr_src[i + q];
        uint4 u = *(const uint4*)(h8 + (size_t)s * 128 + f * 16);
        accum16(acc, u);
    }
    // tail: up to 7 edges, predicated
    if (i < i1) {
        bool valid = (i + q) < i1;
        int e = valid ? (i + q) : i;
        int s = csr_src[e];
        uint4 u = *(const uint4*)(h8 + (size_t)s * 128 + f * 16);
        if (valid) accum16(acc, u);
    }
    // self term in slot 0
    if (q == 0) {
        uint4 u = *(const uint4*)(h8 + (size_t)node * 128 + f * 16);
        accum16(acc, u);
    }
    // combine the 8 slots: lanes f, f+8, ..., f+56 -> lane f
#pragma unroll
    for (int j = 0; j < 16; j++) {
        float v = acc[j];
        v += __shfl_down(v, 32, 64);
        v += __shfl_down(v, 16, 64);
        v += __shfl_down(v, 8, 64);
        acc[j] = v;
    }
    if (q == 0) {
        float dn = dis[node];
        float r[16];
#pragma unroll
        for (int p4 = 0; p4 < 4; p4++) {
            float4 bb = *(const float4*)(bias + f * 16 + p4 * 4);
            r[p4 * 4 + 0] = fmaxf(fmaf(acc[p4 * 4 + 0], dn, bb.x), 0.f);
            r[p4 * 4 + 1] = fmaxf(fmaf(acc[p4 * 4 + 1], dn, bb.y), 0.f);
            r[p4 * 4 + 2] = fmaxf(fmaf(acc[p4 * 4 + 2], dn, bb.z), 0.f);
            r[p4 * 4 + 3] = fmaxf(fmaf(acc[p4 * 4 + 3], dn, bb.w), 0.f);
        }
        unsigned pp[8];   // contiguous array — defined behavior (R13 bug: indexed past a uint4)
#pragma unroll
        for (int j = 0; j < 8; j++) {
            __hip_bfloat162 p = __float22bfloat162_rn(make_float2(r[2 * j], r[2 * j + 1]));
            pp[j] = *(unsigned int*)&p;
        }
        *(uint4*)(out + (size_t)node * 128 + f * 16) = *(const uint4*)&pp[0];
        *(uint4*)(out + (size_t)node * 128 + f * 16 + 8) = *(const uint4*)&pp[4];
    }
}

// ---------------- pooling: 128 rows/block, 16B/lane, gstart-based segments ----------------
#define POOL_ROWS 128
__global__ __launch_bounds__(256) void pool_kernel(const __hip_bfloat16* __restrict__ h,
                                                   const int* __restrict__ batch,
                                                   const int* __restrict__ gstart,
                                                   float* __restrict__ psum, int n) {
    __shared__ float red[16 * 128];
    int tid = threadIdx.x;
    int rr = tid >> 4, fg = tid & 15;
    int r0 = blockIdx.x * POOL_ROWS;
    if (r0 >= n) return;
    int r1 = min(n, r0 + POOL_ROWS);
    int g = batch[r0];
    int seg_lo = r0;
    while (seg_lo < r1) {
        while (gstart[g + 1] <= seg_lo) g++;
        int seg_hi = min(r1, gstart[g + 1]);
        float a[8];
#pragma unroll
        for (int j = 0; j < 8; j++) a[j] = 0.f;
        for (int r = seg_lo + rr; r < seg_hi; r += 16) {
            uint4 u = *(const uint4*)(h + (size_t)r * 128 + fg * 8);
            float2 f0 = __bfloat1622float2(*(__hip_bfloat162*)&u.x);
            float2 f1 = __bfloat1622float2(*(__hip_bfloat162*)&u.y);
            float2 f2 = __bfloat1622float2(*(__hip_bfloat162*)&u.z);
            float2 f3 = __bfloat1622float2(*(__hip_bfloat162*)&u.w);
            a[0] += f0.x; a[1] += f0.y; a[2] += f1.x; a[3] += f1.y;
            a[4] += f2.x; a[5] += f2.y; a[6] += f3.x; a[7] += f3.y;
        }
        *(float4*)&red[rr * 128 + fg * 8] = make_float4(a[0], a[1], a[2], a[3]);
        *(float4*)&red[rr * 128 + fg * 8 + 4] = make_float4(a[4], a[5], a[6], a[7]);
        __syncthreads();
        if (tid < 128) {
            float s = 0.f;
#pragma unroll
            for (int k = 0; k < 16; k++) s += red[k * 128 + tid];
            atomicAdd(&psum[g * 128 + tid], s);
        }
        __syncthreads();
        seg_lo = seg_hi;
    }
}

// ---------------- fused final MLP ----------------
__global__ __launch_bounds__(256) void mlp_kernel(const float* __restrict__ psum,
                                                  const int* __restrict__ gstart,
                                                  const float* __restrict__ sv,
                                                  const float* __restrict__ act,
                                                  const float* __restrict__ Wf1,
                                                  const float* __restrict__ bf1,
                                                  const float* __restrict__ Wf2,
                                                  const float* __restrict__ bf2,
                                                  const float* __restrict__ Wo,
                                                  const float* __restrict__ bo,
                                                  float* __restrict__ out) {
    int g = blockIdx.x, tid = threadIdx.x;
    __shared__ float z[224];
    __shared__ float z1[256];
    __shared__ float red[256];
    if (tid < 128) {
        int c = gstart[g + 1] - gstart[g];
        float cnt = fmaxf((float)c, 1.f);
        z[tid] = psum[g * 128 + tid] / cnt;
    } else if (tid < 192) {
        z[tid] = sv[g * 64 + (tid - 128)];
    } else if (tid < 224) {
        z[tid] = act[g * 32 + (tid - 192)];
    }
    __syncthreads();
    float a = bf1[tid];
    for (int k = 0; k < 224; k++) a = fmaf(z[k], Wf1[k * 256 + tid], a);
    z1[tid] = fmaxf(a, 0.f);
    __syncthreads();
    float b = bf2[tid];
    for (int k = 0; k < 256; k++) b = fmaf(z1[k], Wf2[k * 256 + tid], b);
    b = fmaxf(b, 0.f);
    red[tid] = b * Wo[tid];
    __syncthreads();
    for (int off = 128; off > 0; off >>= 1) {
        if (tid < off) red[tid] += red[tid + off];
        __syncthreads();
    }
    if (tid == 0) out[g] = red[0] + bo[0];
}

// ---------------- launch ----------------
extern "C" void kernel_launch(void* const* d_in, const int* in_sizes, int n_in,
                              void* d_out, int out_size, void* d_ws, size_t ws_size,
                              hipStream_t stream) {
    const float* x   = (const float*)d_in[0];
    const int*   eidx = (const int*)d_in[1];
    const int*   batch = (const int*)d_in[2];
    const float* sv  = (const float*)d_in[3];
    const float* act = (const float*)d_in[4];
    const float* W1  = (const float*)d_in[5];
    const float* b1  = (const float*)d_in[6];
    const float* W2  = (const float*)d_in[7];
    const float* b2  = (const float*)d_in[8];
    const float* Wf1 = (const float*)d_in[9];
    const float* bf1 = (const float*)d_in[10];
    const float* Wf2 = (const float*)d_in[11];
    const float* bf2 = (const float*)d_in[12];
    const float* Wo  = (const float*)d_in[13];
    const float* bo  = (const float*)d_in[14];
    float* out = (float*)d_out;

    const int* srcp = eidx;             // edge_index[0]
    const int* dstp = eidx + N_EDGES;   // edge_index[1]

    char* w = (char*)d_ws;
    int* gcur = (int*)w;               w += (size_t)NBUCK * 4;
    float* psum = (float*)w;           w += (size_t)N_GRAPHS * HDIM * 4;
    int2* rs2 = (int2*)w;              w += (size_t)N_NODES * 8;
    float* dis = (float*)w;            w += (size_t)N_NODES * 4;
    int* gstart = (int*)w;             w += (size_t)(N_GRAPHS + 1) * 4;
    w = (char*)(((uintptr_t)w + 255) & ~(uintptr_t)255);
    int* csr_src = (int*)w;            w += (size_t)NBUCK * CAP * 4;
    w = (char*)(((uintptr_t)w + 255) & ~(uintptr_t)255);
    int* sorted = (int*)w;             w += (size_t)NBUCK * CAP * 4;
    w = (char*)(((uintptr_t)w + 255) & ~(uintptr_t)255);
    __hip_bfloat16* Wt1 = (__hip_bfloat16*)w;   w += (size_t)HDIM * HDIM * 2;
    __hip_bfloat16* Wt2 = (__hip_bfloat16*)w;   w += (size_t)HDIM * HDIM * 2;
    w = (char*)(((uintptr_t)w + 255) & ~(uintptr_t)255);
    unsigned char* hbuf = (unsigned char*)w;    w += (size_t)N_NODES * HDIM;      // fp8
    w = (char*)(((uintptr_t)w + 255) & ~(uintptr_t)255);
    __hip_bfloat16* abuf = (__hip_bfloat16*)w;  w += (size_t)N_NODES * HDIM * 2;  // bf16

    setup_kernel<<<SETUP_NBLK, 256, 0, stream>>>(batch, gstart, W1, W2, Wt1, Wt2, gcur, psum);

    scatter_kernel<<<SCAT_NBLK, 256, 0, stream>>>(srcp, dstp, gcur, sorted, N_EDGES);
    bucket_build_kernel<<<NBUCK, 256, 0, stream>>>(sorted, gcur, rs2, dis, csr_src);

    int gemm_blocks = (N_NODES + 63) / 64;
    int agg_blocks = (N_NODES + 3) / 4;

    gemm_mfma_kernel<true><<<gemm_blocks, 256, 0, stream>>>(x, Wt1, dis, hbuf, N_NODES);
    agg_kernel<<<agg_blocks, 256, 0, stream>>>(hbuf, dis, rs2, csr_src, b1, abuf, N_NODES);
    gemm_mfma_kernel<false><<<gemm_blocks, 256, 0, stream>>>(abuf, Wt2, dis, hbuf, N_NODES);
    agg_kernel<<<agg_blocks, 256, 0, stream>>>(hbuf, dis, rs2, csr_src, b2, abuf, N_NODES);

    pool_kernel<<<(N_NODES + POOL_ROWS - 1) / POOL_ROWS, 256, 0, stream>>>(abuf, batch, gstart, psum, N_NODES);
    mlp_kernel<<<N_GRAPHS, 256, 0, stream>>>(psum, gstart, sv, act, Wf1, bf1, Wf2, bf2, Wo, bo, out);
}

// Round 15
// 331.454 us; speedup vs baseline: 1.0616x; 1.0616x over previous
//
#include <hip/hip_runtime.h>
#include <hip/hip_bf16.h>
#include <stdint.h>

#define N_NODES 100000
#define N_EDGES 1600000
#define N_GRAPHS 64
#define HDIM 128

#define BUCKET_SHIFT 9
#define NBUCK ((N_NODES + 511) >> 9)                  // 196
#define CAP 9216                                      // per-bucket edge capacity (mean 8192 + 11 sigma)
#define SCAT_CHUNK 8192
#define SCAT_NBLK ((N_EDGES + SCAT_CHUNK - 1) / SCAT_CHUNK)  // 196
#define GB_NBLK ((N_NODES + 255) / 256)               // 391

typedef __bf16 bf16x8 __attribute__((ext_vector_type(8)));
typedef float f32x4 __attribute__((ext_vector_type(4)));
typedef float f32x2 __attribute__((ext_vector_type(2)));

// ---------------- fused setup: graph_bounds | transpose W1/W2 | init gcur/psum ----------------
__global__ __launch_bounds__(256) void setup_kernel(const int* __restrict__ batch,
                                                    int* __restrict__ gstart,
                                                    const float* __restrict__ W1,
                                                    const float* __restrict__ W2,
                                                    __hip_bfloat16* __restrict__ Wt1,
                                                    __hip_bfloat16* __restrict__ Wt2,
                                                    int* __restrict__ gcur,
                                                    float* __restrict__ psum) {
    int bid = blockIdx.x;
    if (bid < GB_NBLK) {
        int i = bid * 256 + threadIdx.x;
        if (i >= N_NODES) return;
        int b = batch[i];
        int prev = (i == 0) ? -1 : batch[i - 1];
        for (int g = prev + 1; g <= b; ++g) gstart[g] = i;
        if (i == N_NODES - 1) {
            for (int g = b + 1; g <= N_GRAPHS; ++g) gstart[g] = N_NODES;
        }
    } else if (bid < GB_NBLK + 128) {
        int t = bid - GB_NBLK;
        const float* W = (t < 64) ? W1 : W2;
        __hip_bfloat16* Wt = (t < 64) ? Wt1 : Wt2;
        int bb = t & 63;
        int n = bb * 2 + (threadIdx.x >> 7);
        int k = threadIdx.x & 127;
        Wt[n * 128 + k] = __float2bfloat16(W[k * 128 + n]);
    } else {
        int i = (bid - GB_NBLK - 128) * 256 + threadIdx.x;
        if (i < NBUCK) gcur[i] = i * CAP;
        int j = i - NBUCK;
        if (j >= 0 && j < N_GRAPHS * HDIM) psum[j] = 0.f;
    }
}
#define SETUP_NBLK (GB_NBLK + 128 + (NBUCK + N_GRAPHS * HDIM + 255) / 256)

// ---------------- scatter edges into capacity-strided buckets ----------------
// packed entry: (local_dst << 17) | src   (src < 2^17, local_dst < 512)
__global__ __launch_bounds__(256) void scatter_kernel(const int* __restrict__ src,
                                                      const int* __restrict__ dst,
                                                      int* __restrict__ gcur,
                                                      int* __restrict__ sorted, int E) {
    __shared__ int hist[NBUCK];
    __shared__ int base_s[NBUCK];
    int tid = threadIdx.x;
    int e0 = blockIdx.x * SCAT_CHUNK;
    int sv[SCAT_CHUNK / 256], dv[SCAT_CHUNK / 256];
#pragma unroll
    for (int j = 0; j < SCAT_CHUNK / 256; j++) {
        int e = e0 + (j << 8) + tid;
        if (e < E) { sv[j] = src[e]; dv[j] = dst[e]; } else { sv[j] = -1; dv[j] = -1; }
    }
    if (tid < NBUCK) hist[tid] = 0;
    __syncthreads();
#pragma unroll
    for (int j = 0; j < SCAT_CHUNK / 256; j++)
        if (dv[j] >= 0) atomicAdd(&hist[dv[j] >> BUCKET_SHIFT], 1);
    __syncthreads();
    if (tid < NBUCK) {
        int c = hist[tid];
        base_s[tid] = (c > 0) ? atomicAdd(&gcur[tid], c) : 0;
    }
    __syncthreads();
    if (tid < NBUCK) hist[tid] = 0;
    __syncthreads();
#pragma unroll
    for (int j = 0; j < SCAT_CHUNK / 256; j++) {
        if (dv[j] >= 0) {
            int b = dv[j] >> BUCKET_SHIFT;
            int idx = atomicAdd(&hist[b], 1);
            sorted[base_s[b] + idx] = ((dv[j] & 511) << 17) | sv[j];
        }
    }
}

// ---------------- per-bucket: degree, dis, row (start,end), CSR fill — LDS-staged ----------------
__global__ __launch_bounds__(256) void bucket_build_kernel(const int* __restrict__ sorted,
                                                           const int* __restrict__ gcur,
                                                           int2* __restrict__ rs2,
                                                           float* __restrict__ dis,
                                                           int* __restrict__ csr_src) {
    __shared__ int edges[CAP];     // 36 KB — bucket's edge list staged once
    __shared__ int cnt[512];
    __shared__ int excl[512];
    __shared__ int ps[256];
    int b = blockIdx.x, tid = threadIdx.x;
    cnt[tid] = 0; cnt[tid + 256] = 0;
    int node0 = b << BUCKET_SHIFT;
    int lo = b * CAP, hi = gcur[b];
    int ne = hi - lo;
    for (int i = tid; i < ne; i += 256) edges[i] = sorted[lo + i];
    __syncthreads();
    for (int i = tid; i < ne; i += 256)
        atomicAdd(&cnt[((unsigned)edges[i]) >> 17], 1);
    __syncthreads();
    // pair-scan of 512 counts with 256 threads
    int c0 = cnt[2 * tid], c1 = cnt[2 * tid + 1];
    ps[tid] = c0 + c1;
    __syncthreads();
#pragma unroll
    for (int off = 1; off < 256; off <<= 1) {
        int t = (tid >= off) ? ps[tid - off] : 0;
        __syncthreads();
        ps[tid] += t;
        __syncthreads();
    }
    int pex = ps[tid] - (c0 + c1);
    excl[2 * tid] = pex;
    excl[2 * tid + 1] = pex + c0;
    __syncthreads();
#pragma unroll
    for (int k = 0; k < 2; k++) {
        int li = tid + k * 256;
        int node = node0 + li;
        if (node < N_NODES) {
            int st = lo + excl[li];
            int c = cnt[li];
            rs2[node] = make_int2(st, st + c);
            dis[node] = rsqrtf((float)c + 1.0f);
        }
    }
    // reuse cnt as fill cursors
    cnt[tid] = 0; cnt[tid + 256] = 0;
    __syncthreads();
    for (int i = tid; i < ne; i += 256) {
        int v = edges[i];
        int li = ((unsigned)v) >> 17;
        int idx = atomicAdd(&cnt[li], 1);
        csr_src[lo + excl[li] + idx] = v & 0x1FFFF;
    }
}

// ---------------- MFMA GEMM: C_fp8[r][c] = e4m3( (sum_k A[r][k] W[k][c]) * scale[r] )
template<bool A_FP32>
__global__ __launch_bounds__(256) void gemm_mfma_kernel(const void* __restrict__ Av,
                                                        const __hip_bfloat16* __restrict__ Wt,
                                                        const float* __restrict__ scale,
                                                        unsigned char* __restrict__ C, int nrows) {
    __shared__ float Cs[64 * 132];
    int tid = threadIdx.x;
    int wave = tid >> 6, lane = tid & 63;
    int quad = lane >> 4, l16 = lane & 15;
    int row0 = blockIdx.x * 64;
    int arow = row0 + wave * 16 + l16;
    int arow_c = min(arow, nrows - 1);

    const __hip_bfloat16* A16 = (const __hip_bfloat16*)Av;
    const float* A32 = (const float*)Av;

    f32x4 acc[8];
#pragma unroll
    for (int t = 0; t < 8; t++) acc[t] = (f32x4){0.f, 0.f, 0.f, 0.f};

#pragma unroll
    for (int kt = 0; kt < 4; kt++) {
        int kbase = kt * 32 + quad * 8;
        union { bf16x8 v; __hip_bfloat16 h[8]; uint4 u; } au;
        if (A_FP32) {
            const float* ap = A32 + (size_t)arow_c * 128 + kbase;
            float4 u0 = *(const float4*)ap;
            float4 u1 = *(const float4*)(ap + 4);
            au.h[0] = __float2bfloat16(u0.x); au.h[1] = __float2bfloat16(u0.y);
            au.h[2] = __float2bfloat16(u0.z); au.h[3] = __float2bfloat16(u0.w);
            au.h[4] = __float2bfloat16(u1.x); au.h[5] = __float2bfloat16(u1.y);
            au.h[6] = __float2bfloat16(u1.z); au.h[7] = __float2bfloat16(u1.w);
        } else {
            au.u = *(const uint4*)(A16 + (size_t)arow_c * 128 + kbase);
        }
#pragma unroll
        for (int t = 0; t < 8; t++) {
            bf16x8 b = *(const bf16x8*)(Wt + (size_t)(t * 16 + l16) * 128 + kbase);
            acc[t] = __builtin_amdgcn_mfma_f32_16x16x32_bf16(au.v, b, acc[t], 0, 0, 0);
        }
    }

    int rbase = wave * 16 + quad * 4;
    float s[4];
#pragma unroll
    for (int r = 0; r < 4; r++) s[r] = scale[min(row0 + rbase + r, nrows - 1)];
#pragma unroll
    for (int t = 0; t < 8; t++) {
#pragma unroll
        for (int r = 0; r < 4; r++)
            Cs[(rbase + r) * 132 + t * 16 + l16] = acc[t][r] * s[r];
    }
    __syncthreads();

#pragma unroll
    for (int p = 0; p < 4; p++) {
        int g = p * 256 + tid;
        int row = g >> 4, c8 = (g & 15) * 8;
        int grow = row0 + row;
        if (grow < nrows) {
            const float* cp = &Cs[row * 132 + c8];
            float4 v0 = *(const float4*)cp;
            float4 v1 = *(const float4*)(cp + 4);
            int w0 = __builtin_amdgcn_cvt_pk_fp8_f32(v0.x, v0.y, 0, false);
            w0 = __builtin_amdgcn_cvt_pk_fp8_f32(v0.z, v0.w, w0, true);
            int w1 = __builtin_amdgcn_cvt_pk_fp8_f32(v1.x, v1.y, 0, false);
            w1 = __builtin_amdgcn_cvt_pk_fp8_f32(v1.z, v1.w, w1, true);
            *(uint2*)(C + (size_t)grow * 128 + c8) = make_uint2((unsigned)w0, (unsigned)w1);
        }
    }
}

// ---------------- GCN aggregation (R12 winner): 4 edges/gather, 2-wide unroll ----------------
__device__ __forceinline__ void accum8(float* acc, uint2 u) {
    f32x2 d0 = __builtin_amdgcn_cvt_pk_f32_fp8((int)u.x, false);
    f32x2 d1 = __builtin_amdgcn_cvt_pk_f32_fp8((int)u.x, true);
    f32x2 d2 = __builtin_amdgcn_cvt_pk_f32_fp8((int)u.y, false);
    f32x2 d3 = __builtin_amdgcn_cvt_pk_f32_fp8((int)u.y, true);
    acc[0] += d0[0]; acc[1] += d0[1]; acc[2] += d1[0]; acc[3] += d1[1];
    acc[4] += d2[0]; acc[5] += d2[1]; acc[6] += d3[0]; acc[7] += d3[1];
}

__global__ __launch_bounds__(256) void agg_kernel(const unsigned char* __restrict__ h8,
                                                  const float* __restrict__ dis,
                                                  const int2* __restrict__ rs2,
                                                  const int* __restrict__ csr_src,
                                                  const float* __restrict__ bias,
                                                  __hip_bfloat16* __restrict__ out, int n) {
    int node = blockIdx.x * 4 + (threadIdx.x >> 6);
    if (node >= n) return;
    int lane = threadIdx.x & 63;
    int q = lane >> 4, f = lane & 15;
    float acc[8];
#pragma unroll
    for (int j = 0; j < 8; j++) acc[j] = 0.f;
    int2 se = rs2[node];
    int i = se.x, i1 = se.y;
    // 2-wide unroll: two independent 4-edge gathers in flight
    for (; i + 8 <= i1; i += 8) {
        int s0 = csr_src[i + q];
        int s1 = csr_src[i + 4 + q];
        uint2 u0 = *(const uint2*)(h8 + (size_t)s0 * 128 + f * 8);
        uint2 u1 = *(const uint2*)(h8 + (size_t)s1 * 128 + f * 8);
        accum8(acc, u0);
        accum8(acc, u1);
    }
    for (; i + 4 <= i1; i += 4) {
        int s = csr_src[i + q];
        uint2 u = *(const uint2*)(h8 + (size_t)s * 128 + f * 8);
        accum8(acc, u);
    }
    // tail: up to 3 edges, predicated
    if (i < i1) {
        bool valid = (i + q) < i1;
        int e = valid ? (i + q) : (i1 - 1);
        int s = csr_src[e];
        uint2 u = *(const uint2*)(h8 + (size_t)s * 128 + f * 8);
        if (valid) accum8(acc, u);
    }
    // self term in quarter 0
    if (q == 0) {
        uint2 u = *(const uint2*)(h8 + (size_t)node * 128 + f * 8);
        accum8(acc, u);
    }
    // combine quarters: lanes f, f+16, f+32, f+48 -> lane f
#pragma unroll
    for (int j = 0; j < 8; j++) {
        float v = acc[j];
        v += __shfl_down(v, 32, 64);
        v += __shfl_down(v, 16, 64);
        acc[j] = v;
    }
    if (q == 0) {
        float dn = dis[node];
        float4 b0 = *(const float4*)(bias + f * 8);
        float4 b1 = *(const float4*)(bias + f * 8 + 4);
        float r0 = fmaxf(fmaf(acc[0], dn, b0.x), 0.f);
        float r1 = fmaxf(fmaf(acc[1], dn, b0.y), 0.f);
        float r2 = fmaxf(fmaf(acc[2], dn, b0.z), 0.f);
        float r3 = fmaxf(fmaf(acc[3], dn, b0.w), 0.f);
        float r4 = fmaxf(fmaf(acc[4], dn, b1.x), 0.f);
        float r5 = fmaxf(fmaf(acc[5], dn, b1.y), 0.f);
        float r6 = fmaxf(fmaf(acc[6], dn, b1.z), 0.f);
        float r7 = fmaxf(fmaf(acc[7], dn, b1.w), 0.f);
        __hip_bfloat162 p0 = __float22bfloat162_rn(make_float2(r0, r1));
        __hip_bfloat162 p1 = __float22bfloat162_rn(make_float2(r2, r3));
        __hip_bfloat162 p2 = __float22bfloat162_rn(make_float2(r4, r5));
        __hip_bfloat162 p3 = __float22bfloat162_rn(make_float2(r6, r7));
        uint4 pk;
        pk.x = *(unsigned int*)&p0; pk.y = *(unsigned int*)&p1;
        pk.z = *(unsigned int*)&p2; pk.w = *(unsigned int*)&p3;
        *(uint4*)(out + (size_t)node * 128 + f * 8) = pk;
    }
}

// ---------------- pooling: 128 rows/block, 16B/lane, gstart-based segments ----------------
#define POOL_ROWS 128
__global__ __launch_bounds__(256) void pool_kernel(const __hip_bfloat16* __restrict__ h,
                                                   const int* __restrict__ batch,
                                                   const int* __restrict__ gstart,
                                                   float* __restrict__ psum, int n) {
    __shared__ float red[16 * 128];
    int tid = threadIdx.x;
    int rr = tid >> 4, fg = tid & 15;
    int r0 = blockIdx.x * POOL_ROWS;
    if (r0 >= n) return;
    int r1 = min(n, r0 + POOL_ROWS);
    int g = batch[r0];
    int seg_lo = r0;
    while (seg_lo < r1) {
        while (gstart[g + 1] <= seg_lo) g++;
        int seg_hi = min(r1, gstart[g + 1]);
        float a[8];
#pragma unroll
        for (int j = 0; j < 8; j++) a[j] = 0.f;
        for (int r = seg_lo + rr; r < seg_hi; r += 16) {
            uint4 u = *(const uint4*)(h + (size_t)r * 128 + fg * 8);
            float2 f0 = __bfloat1622float2(*(__hip_bfloat162*)&u.x);
            float2 f1 = __bfloat1622float2(*(__hip_bfloat162*)&u.y);
            float2 f2 = __bfloat1622float2(*(__hip_bfloat162*)&u.z);
            float2 f3 = __bfloat1622float2(*(__hip_bfloat162*)&u.w);
            a[0] += f0.x; a[1] += f0.y; a[2] += f1.x; a[3] += f1.y;
            a[4] += f2.x; a[5] += f2.y; a[6] += f3.x; a[7] += f3.y;
        }
        *(float4*)&red[rr * 128 + fg * 8] = make_float4(a[0], a[1], a[2], a[3]);
        *(float4*)&red[rr * 128 + fg * 8 + 4] = make_float4(a[4], a[5], a[6], a[7]);
        __syncthreads();
        if (tid < 128) {
            float s = 0.f;
#pragma unroll
            for (int k = 0; k < 16; k++) s += red[k * 128 + tid];
            atomicAdd(&psum[g * 128 + tid], s);
        }
        __syncthreads();
        seg_lo = seg_hi;
    }
}

// ---------------- fused final MLP ----------------
__global__ __launch_bounds__(256) void mlp_kernel(const float* __restrict__ psum,
                                                  const int* __restrict__ gstart,
                                                  const float* __restrict__ sv,
                                                  const float* __restrict__ act,
                                                  const float* __restrict__ Wf1,
                                                  const float* __restrict__ bf1,
                                                  const float* __restrict__ Wf2,
                                                  const float* __restrict__ bf2,
                                                  const float* __restrict__ Wo,
                                                  const float* __restrict__ bo,
                                                  float* __restrict__ out) {
    int g = blockIdx.x, tid = threadIdx.x;
    __shared__ float z[224];
    __shared__ float z1[256];
    __shared__ float red[256];
    if (tid < 128) {
        int c = gstart[g + 1] - gstart[g];
        float cnt = fmaxf((float)c, 1.f);
        z[tid] = psum[g * 128 + tid] / cnt;
    } else if (tid < 192) {
        z[tid] = sv[g * 64 + (tid - 128)];
    } else if (tid < 224) {
        z[tid] = act[g * 32 + (tid - 192)];
    }
    __syncthreads();
    float a = bf1[tid];
    for (int k = 0; k < 224; k++) a = fmaf(z[k], Wf1[k * 256 + tid], a);
    z1[tid] = fmaxf(a, 0.f);
    __syncthreads();
    float b = bf2[tid];
    for (int k = 0; k < 256; k++) b = fmaf(z1[k], Wf2[k * 256 + tid], b);
    b = fmaxf(b, 0.f);
    red[tid] = b * Wo[tid];
    __syncthreads();
    for (int off = 128; off > 0; off >>= 1) {
        if (tid < off) red[tid] += red[tid + off];
        __syncthreads();
    }
    if (tid == 0) out[g] = red[0] + bo[0];
}

// ---------------- launch ----------------
extern "C" void kernel_launch(void* const* d_in, const int* in_sizes, int n_in,
                              void* d_out, int out_size, void* d_ws, size_t ws_size,
                              hipStream_t stream) {
    const float* x   = (const float*)d_in[0];
    const int*   eidx = (const int*)d_in[1];
    const int*   batch = (const int*)d_in[2];
    const float* sv  = (const float*)d_in[3];
    const float* act = (const float*)d_in[4];
    const float* W1  = (const float*)d_in[5];
    const float* b1  = (const float*)d_in[6];
    const float* W2  = (const float*)d_in[7];
    const float* b2  = (const float*)d_in[8];
    const float* Wf1 = (const float*)d_in[9];
    const float* bf1 = (const float*)d_in[10];
    const float* Wf2 = (const float*)d_in[11];
    const float* bf2 = (const float*)d_in[12];
    const float* Wo  = (const float*)d_in[13];
    const float* bo  = (const float*)d_in[14];
    float* out = (float*)d_out;

    const int* srcp = eidx;             // edge_index[0]
    const int* dstp = eidx + N_EDGES;   // edge_index[1]

    char* w = (char*)d_ws;
    int* gcur = (int*)w;               w += (size_t)NBUCK * 4;
    float* psum = (float*)w;           w += (size_t)N_GRAPHS * HDIM * 4;
    int2* rs2 = (int2*)w;              w += (size_t)N_NODES * 8;
    float* dis = (float*)w;            w += (size_t)N_NODES * 4;
    int* gstart = (int*)w;             w += (size_t)(N_GRAPHS + 1) * 4;
    w = (char*)(((uintptr_t)w + 255) & ~(uintptr_t)255);
    int* csr_src = (int*)w;            w += (size_t)NBUCK * CAP * 4;
    w = (char*)(((uintptr_t)w + 255) & ~(uintptr_t)255);
    int* sorted = (int*)w;             w += (size_t)NBUCK * CAP * 4;
    w = (char*)(((uintptr_t)w + 255) & ~(uintptr_t)255);
    __hip_bfloat16* Wt1 = (__hip_bfloat16*)w;   w += (size_t)HDIM * HDIM * 2;
    __hip_bfloat16* Wt2 = (__hip_bfloat16*)w;   w += (size_t)HDIM * HDIM * 2;
    w = (char*)(((uintptr_t)w + 255) & ~(uintptr_t)255);
    unsigned char* hbuf = (unsigned char*)w;    w += (size_t)N_NODES * HDIM;      // fp8
    w = (char*)(((uintptr_t)w + 255) & ~(uintptr_t)255);
    __hip_bfloat16* abuf = (__hip_bfloat16*)w;  w += (size_t)N_NODES * HDIM * 2;  // bf16

    setup_kernel<<<SETUP_NBLK, 256, 0, stream>>>(batch, gstart, W1, W2, Wt1, Wt2, gcur, psum);

    scatter_kernel<<<SCAT_NBLK, 256, 0, stream>>>(srcp, dstp, gcur, sorted, N_EDGES);
    bucket_build_kernel<<<NBUCK, 256, 0, stream>>>(sorted, gcur, rs2, dis, csr_src);

    int gemm_blocks = (N_NODES + 63) / 64;
    int agg_blocks = (N_NODES + 3) / 4;

    gemm_mfma_kernel<true><<<gemm_blocks, 256, 0, stream>>>(x, Wt1, dis, hbuf, N_NODES);
    agg_kernel<<<agg_blocks, 256, 0, stream>>>(hbuf, dis, rs2, csr_src, b1, abuf, N_NODES);
    gemm_mfma_kernel<false><<<gemm_blocks, 256, 0, stream>>>(abuf, Wt2, dis, hbuf, N_NODES);
    agg_kernel<<<agg_blocks, 256, 0, stream>>>(hbuf, dis, rs2, csr_src, b2, abuf, N_NODES);

    pool_kernel<<<(N_NODES + POOL_ROWS - 1) / POOL_ROWS, 256, 0, stream>>>(abuf, batch, gstart, psum, N_NODES);
    mlp_kernel<<<N_GRAPHS, 256, 0, stream>>>(psum, gstart, sv, act, Wf1, bf1, Wf2, bf2, Wo, bo, out);
}